// Round 13
// baseline (207.409 us; speedup 1.0000x reference)
//
#include <hip/hip_runtime.h>
#include <hip/hip_bf16.h>

#define N_ 8
#define C_ 32
#define H_ 64
#define W_ 64
#define HW_ (H_*W_)
#define NHW_ (N_*HW_)
#define INTER_ 64
#define BC_ 108
#define KS_ 7
#define K2_ (KS_*KS_)
#define NB_ 6
#define TB_ 18
#define OUT_ 64
#define DDIM_ (C_*NB_)   // 192
#define P2CH_ 288        // 9 tp-pairs * 32 c

typedef __attribute__((ext_vector_type(8))) short short8;
typedef __attribute__((ext_vector_type(4))) float f32x4;

__device__ __forceinline__ unsigned short f2bf(float f) {
    union { float f; unsigned u; } v; v.f = f;
    unsigned r = v.u + 0x7fffu + ((v.u >> 16) & 1u);
    return (unsigned short)(r >> 16);
}
__device__ __forceinline__ float bf2f(unsigned short h) {
    return __uint_as_float((unsigned int)h << 16);
}

__device__ __forceinline__ short8 frag4(const unsigned int* p) {
    union { unsigned int u[4]; short8 s; } v;
    v.u[0] = p[0]; v.u[1] = p[1]; v.u[2] = p[2]; v.u[3] = p[3];
    return v.s;
}

__inline__ __device__ float wave_reduce_sum(float v) {
    #pragma unroll
    for (int off = 32; off > 0; off >>= 1) v += __shfl_down(v, off);
    return v;
}

// ---------------------------------------------------------------------------
// k_prep: x NCHW f32 -> xb NHWC bf16 ; conv weights -> [s][co][ci] bf16;
// out_w -> bf16 hi/lo. grid 920.
__global__ __launch_bounds__(256) void k_prep(const float* __restrict__ x,
                                              const float* __restrict__ w1,
                                              const float* __restrict__ w2,
                                              const float* __restrict__ ow,
                                              unsigned short* __restrict__ xb,
                                              unsigned short* __restrict__ wb1,
                                              unsigned short* __restrict__ wb2,
                                              unsigned short* __restrict__ wbp) {
    __shared__ unsigned short sT[64 * 36];
    int pbid = blockIdx.x, t = threadIdx.x;
    if (pbid < 512) {
        int n = pbid >> 6, hw0 = (pbid << 6) & 4095;
        for (int i = t; i < 2048; i += 256) {
            int c = i >> 6, px = i & 63;
            float v = x[(((size_t)n * C_ + c) << 12) + hw0 + px];
            sT[px * 36 + c] = f2bf(v);
        }
        __syncthreads();
        unsigned int* xd = (unsigned int*)xb;
        for (int i = t; i < 1024; i += 256) {
            int px = i >> 4, cw = i & 15;
            unsigned int lo = sT[px * 36 + cw * 2], hi = sT[px * 36 + cw * 2 + 1];
            xd[(((size_t)n << 12) + hw0 + px) * 16 + cw] = lo | (hi << 16);
        }
    } else if (pbid < 584) {
        int i = (pbid - 512) * 256 + t;       // < 18432 = 9*64*32
        int ci = i & 31, co = (i >> 5) & 63, s = i >> 11;
        wb1[i] = f2bf(w1[((co << 5) + ci) * 9 + s]);
    } else if (pbid < 872) {
        int i = (pbid - 584) * 256 + t;       // < 73728 = 9*128*64
        int ci = i & 63, co = (i >> 6) & 127, s = i >> 13;
        unsigned short v = 0;
        if (co < BC_) v = f2bf(w2[((co << 6) + ci) * 9 + s]);
        wb2[i] = v;
    } else {
        int i = (pbid - 872) * 256 + t;       // < 12288 = 64*192
        if (i < OUT_ * DDIM_) {
            float v = ow[i];
            unsigned short hi = f2bf(v);
            wbp[i] = hi;
            wbp[OUT_ * DDIM_ + i] = f2bf(v - bf2f(hi));
        }
    }
}

// ---------------------------------------------------------------------------
// MFMA conv3x3 (pad=1), stage-once (conv1 only now)
template<int CIN, int COG, int ROWS, int WPAD, int NCOQ>
__global__ __launch_bounds__(256) void k_conv3(const unsigned short* __restrict__ xb,
                                               const unsigned short* __restrict__ wb,
                                               const float* __restrict__ bias,
                                               float* __restrict__ y,
                                               int COUT_real) {
    constexpr int CPAD = CIN + 8;
    constexpr int NSLC = (ROWS + 2) * 66;
    constexpr int MT = COG / 16;
    constexpr int NTW = ROWS;
    constexpr int KSTEPS = CIN / 32;
    __shared__ unsigned short sx[NSLC * CPAD];
    __shared__ unsigned short sw[9 * COG * CPAD];

    int bid = blockIdx.x;
    int coq = bid % NCOQ;
    int rp = (bid / NCOQ) % (H_ / ROWS);
    int n = bid / (NCOQ * (H_ / ROWS));
    int h0 = rp * ROWS;
    int co0 = coq * COG;
    int t = threadIdx.x;
    int lane = t & 63, wv = t >> 6;
    int q = lane >> 4, n15 = lane & 15;

    {
        const unsigned int* xg = (const unsigned int*)xb + (size_t)n * HW_ * (CIN / 2);
        unsigned int* sxd = (unsigned int*)sx;
        constexpr int DW = CIN / 2;
        constexpr int DWPT = DW / 8;
        int part = t & 7;
        for (int sl = (t >> 3); sl < NSLC; sl += 32) {
            int r = sl / 66, col = sl % 66;
            int hh = h0 - 1 + r, ww = col - 1;
            unsigned int v[DWPT];
            #pragma unroll
            for (int i = 0; i < DWPT; i++) v[i] = 0;
            if (hh >= 0 && hh < H_ && ww >= 0 && ww < W_) {
                const unsigned int* gp = xg + (size_t)(hh * W_ + ww) * DW + part * DWPT;
                #pragma unroll
                for (int i = 0; i < DWPT; i++) v[i] = gp[i];
            }
            unsigned int* d = sxd + sl * (CPAD / 2) + part * DWPT;
            #pragma unroll
            for (int i = 0; i < DWPT; i++) d[i] = v[i];
        }
    }
    {
        const unsigned int* wg = (const unsigned int*)wb;
        unsigned int* swd = (unsigned int*)sw;
        constexpr int TOT = 9 * COG * (CIN / 2);
        for (int e = t; e < TOT; e += 256) {
            int s_co = e / (CIN / 2), cw = e % (CIN / 2);
            int s = s_co / COG, co = s_co % COG;
            swd[s_co * (CPAD / 2) + cw] = wg[((size_t)s * WPAD + co0 + co) * (CIN / 2) + cw];
        }
    }
    __syncthreads();

    f32x4 acc[NTW][MT];
    #pragma unroll
    for (int a = 0; a < NTW; a++)
        #pragma unroll
        for (int m = 0; m < MT; m++) acc[a][m] = (f32x4){0.f, 0.f, 0.f, 0.f};

    #pragma unroll
    for (int s = 0; s < 9; s++) {
        int dy = s / 3, dx = s % 3;
        #pragma unroll
        for (int kc = 0; kc < KSTEPS; kc++) {
            int ci0 = kc * 32;
            short8 bfr[NTW];
            #pragma unroll
            for (int ntl = 0; ntl < NTW; ntl++) {
                int nt = wv * NTW + ntl;
                int r_out = nt >> 2, col0 = (nt & 3) * 16;
                bfr[ntl] = *(const short8*)(sx + ((r_out + dy) * 66 + col0 + n15 + dx) * CPAD + ci0 + q * 8);
            }
            #pragma unroll
            for (int mt = 0; mt < MT; mt++) {
                short8 afr = *(const short8*)(sw + ((s * COG) + mt * 16 + n15) * CPAD + ci0 + q * 8);
                #pragma unroll
                for (int ntl = 0; ntl < NTW; ntl++)
                    acc[ntl][mt] = __builtin_amdgcn_mfma_f32_16x16x32_bf16(afr, bfr[ntl], acc[ntl][mt], 0, 0, 0);
            }
        }
    }

    #pragma unroll
    for (int ntl = 0; ntl < NTW; ntl++) {
        int nt = wv * NTW + ntl;
        int h = h0 + (nt >> 2), wcol = (nt & 3) * 16 + n15;
        #pragma unroll
        for (int mt = 0; mt < MT; mt++) {
            #pragma unroll
            for (int reg = 0; reg < 4; reg++) {
                int co = co0 + mt * 16 + q * 4 + reg;
                if (co < COUT_real)
                    y[(((size_t)n * COUT_real + co) << 12) + h * W_ + wcol] = acc[ntl][mt][reg] + bias[co];
            }
        }
    }
}

// ---------------------------------------------------------------------------
// k_cpv: merged conv2 (MFMA) + pconv (VALU) — independent work, complementary
// pipes, interleaved 7:4 via bid%11 so each residency round mixes both.
// grid 2816 = 256*(7 conv2 + 4 pconv).
__global__ __launch_bounds__(256) void k_cpv(const unsigned short* __restrict__ y1b,
                                             const unsigned short* __restrict__ wb2,
                                             const float* __restrict__ bias,
                                             float* __restrict__ y2,
                                             const float* __restrict__ x,
                                             const float* __restrict__ bases,
                                             unsigned int* __restrict__ P2) {
    __shared__ __align__(16) char smem[58752];
    int bid = blockIdx.x, t = threadIdx.x;
    int grp = bid / 11, sub = bid % 11;
    int lane = t & 63, wv = t >> 6;

    if (sub < 7) {
        // ----- conv2: CIN=64, COG=16, ROWS=2, WPAD=128, NCOQ=7
        constexpr int CPAD = 72, NSLC = 264;
        unsigned short* sx = (unsigned short*)smem;            // 264*72 sh
        unsigned short* sw = sx + NSLC * CPAD;                 // 9*16*72 sh
        int cid = grp * 7 + sub;           // 0..1791
        int coq = cid % 7;
        int rp = (cid / 7) % 32;
        int n = cid / (7 * 32);
        int h0 = rp * 2;
        int co0 = coq * 16;
        int q = lane >> 4, n15 = lane & 15;

        {
            const unsigned int* xg = (const unsigned int*)y1b + (size_t)n * HW_ * 32;
            unsigned int* sxd = (unsigned int*)sx;
            int part = t & 7;
            for (int sl = (t >> 3); sl < NSLC; sl += 32) {
                int r = sl / 66, col = sl % 66;
                int hh = h0 - 1 + r, ww = col - 1;
                unsigned int v[4];
                #pragma unroll
                for (int i = 0; i < 4; i++) v[i] = 0;
                if (hh >= 0 && hh < H_ && ww >= 0 && ww < W_) {
                    const unsigned int* gp = xg + (size_t)(hh * W_ + ww) * 32 + part * 4;
                    #pragma unroll
                    for (int i = 0; i < 4; i++) v[i] = gp[i];
                }
                unsigned int* d = sxd + sl * 36 + part * 4;
                #pragma unroll
                for (int i = 0; i < 4; i++) d[i] = v[i];
            }
        }
        {
            const unsigned int* wg = (const unsigned int*)wb2;
            unsigned int* swd = (unsigned int*)sw;
            for (int e = t; e < 9 * 16 * 32; e += 256) {
                int s_co = e / 32, cw = e % 32;
                int s = s_co / 16, co = s_co % 16;
                swd[s_co * 36 + cw] = wg[((size_t)s * 128 + co0 + co) * 32 + cw];
            }
        }
        __syncthreads();

        f32x4 acc[2];
        acc[0] = (f32x4){0.f, 0.f, 0.f, 0.f};
        acc[1] = (f32x4){0.f, 0.f, 0.f, 0.f};

        #pragma unroll
        for (int s = 0; s < 9; s++) {
            int dy = s / 3, dx = s % 3;
            #pragma unroll
            for (int kc = 0; kc < 2; kc++) {
                int ci0 = kc * 32;
                short8 bfr[2];
                #pragma unroll
                for (int ntl = 0; ntl < 2; ntl++) {
                    int nt = wv * 2 + ntl;
                    int r_out = nt >> 2, col0 = (nt & 3) * 16;
                    bfr[ntl] = *(const short8*)(sx + ((r_out + dy) * 66 + col0 + n15 + dx) * 72 + ci0 + q * 8);
                }
                short8 afr = *(const short8*)(sw + (s * 16 + n15) * 72 + ci0 + q * 8);
                acc[0] = __builtin_amdgcn_mfma_f32_16x16x32_bf16(afr, bfr[0], acc[0], 0, 0, 0);
                acc[1] = __builtin_amdgcn_mfma_f32_16x16x32_bf16(afr, bfr[1], acc[1], 0, 0, 0);
            }
        }

        #pragma unroll
        for (int ntl = 0; ntl < 2; ntl++) {
            int nt = wv * 2 + ntl;
            int h = h0 + (nt >> 2), wcol = (nt & 3) * 16 + n15;
            #pragma unroll
            for (int reg = 0; reg < 4; reg++) {
                int co = co0 + q * 4 + reg;
                if (co < BC_)
                    y2[(((size_t)n * BC_ + co) << 12) + h * W_ + wcol] = acc[ntl][reg] + bias[co];
            }
        }
    } else {
        // ----- pconv: P2[n][tp*32+c][h][w] packs bases(2tp,2tp+1) 7x7-corr
        float (*sx)[44] = (float(*)[44])smem;
        int pb = grp * 4 + (sub - 7);      // 0..1023
        int rq = pb & 3;
        int c  = (pb >> 2) & 31;
        int n  = pb >> 7;
        int r0 = rq << 4;

        const float* xc = x + (((size_t)n * C_ + c) << 12);
        #pragma unroll
        for (int j = 0; j < 6; j++) {
            int p = wv + 4 * j;
            if (p < 22) {
                int grow = r0 - 3 + p;
                bool rowok = (grow >= 0 && grow < H_);
                int wx = lane - 3;
                float v = 0.f;
                if (rowok && wx >= 0) v = xc[(grow << 6) + wx];
                sx[lane][p] = v;
                if (lane < 6) {
                    int wx2 = 61 + lane;
                    float v2 = 0.f;
                    if (rowok && wx2 < W_) v2 = xc[(grow << 6) + wx2];
                    sx[64 + lane][p] = v2;
                }
            }
        }
        __syncthreads();

        int rb = wv * 4;
        float a0[9][4], a1[9][4];
        #pragma unroll
        for (int tp = 0; tp < 9; tp++)
            #pragma unroll
            for (int rr = 0; rr < 4; rr++) { a0[tp][rr] = 0.f; a1[tp][rr] = 0.f; }

        #pragma unroll 1
        for (int kx = 0; kx < 7; kx++) {
            float rw[12];
            const float* sp = &sx[lane + kx][rb];
            #pragma unroll
            for (int qq = 0; qq < 3; qq++) {
                float4 r4 = *(const float4*)(sp + qq * 4);
                rw[qq * 4 + 0] = r4.x; rw[qq * 4 + 1] = r4.y;
                rw[qq * 4 + 2] = r4.z; rw[qq * 4 + 3] = r4.w;
            }
            #pragma unroll
            for (int tp = 0; tp < 9; tp++) {
                #pragma unroll
                for (int ky = 0; ky < 7; ky++) {
                    float w0 = bases[(2 * tp) * K2_ + ky * 7 + kx];
                    float w1v = bases[(2 * tp + 1) * K2_ + ky * 7 + kx];
                    #pragma unroll
                    for (int rr = 0; rr < 4; rr++) {
                        float xv = rw[rr + ky];
                        a0[tp][rr] += xv * w0;
                        a1[tp][rr] += xv * w1v;
                    }
                }
            }
        }

        #pragma unroll
        for (int tp = 0; tp < 9; tp++)
            #pragma unroll
            for (int rr = 0; rr < 4; rr++) {
                int gr = r0 + rb + rr;
                unsigned int pk = (unsigned int)f2bf(a0[tp][rr]) | ((unsigned int)f2bf(a1[tp][rr]) << 16);
                P2[(((size_t)n * P2CH_ + tp * 32 + c) << 12) + (gr << 6) + lane] = pk;
            }
    }
}

// ---------------------------------------------------------------------------
__global__ __launch_bounds__(256) void k_bnpart(const float* __restrict__ y,
                                                float2* __restrict__ part, int Cout) {
    int bid = blockIdx.x;
    int c = bid >> 3, n = bid & 7;
    int t = threadIdx.x;
    const float* p = y + (((size_t)n * Cout + c) << 12) + t * 16;
    float s = 0.f, s2 = 0.f;
    #pragma unroll
    for (int j = 0; j < 4; j++) {
        float4 v = *(const float4*)(p + j * 4);
        s += v.x + v.y + v.z + v.w;
        s2 += v.x * v.x + v.y * v.y + v.z * v.z + v.w * v.w;
    }
    s = wave_reduce_sum(s);
    s2 = wave_reduce_sum(s2);
    __shared__ float sm[8];
    int wid = t >> 6, lane = t & 63;
    if (lane == 0) { sm[wid] = s; sm[4 + wid] = s2; }
    __syncthreads();
    if (t == 0) {
        float2 r;
        r.x = sm[0] + sm[1] + sm[2] + sm[3];
        r.y = sm[4] + sm[5] + sm[6] + sm[7];
        part[c * 8 + n] = r;
    }
}

// ---------------------------------------------------------------------------
// y1 NCHW f32 -> tanh(bn) -> y1b NHWC bf16
__global__ __launch_bounds__(256) void k_bntr(const float* __restrict__ y1,
                                              const float2* __restrict__ part,
                                              const float* __restrict__ g,
                                              const float* __restrict__ bb,
                                              unsigned short* __restrict__ y1b) {
    __shared__ unsigned short sT[64 * 68];
    __shared__ float scs[INTER_], shs[INTER_];
    int bid = blockIdx.x, t = threadIdx.x;
    int n = bid >> 6, hw0 = (bid << 6) & 4095;
    if (t < INTER_) {
        float s = 0.f, s2 = 0.f;
        #pragma unroll
        for (int j = 0; j < 8; j++) { float2 p = part[t * 8 + j]; s += p.x; s2 += p.y; }
        float mu = s / (float)NHW_, var = s2 / (float)NHW_ - mu * mu;
        float sc = g[t] * rsqrtf(var + 1e-5f);
        scs[t] = sc; shs[t] = bb[t] - mu * sc;
    }
    __syncthreads();
    for (int i = t; i < 4096; i += 256) {
        int c = i >> 6, px = i & 63;
        float v = y1[(((size_t)n * INTER_ + c) << 12) + hw0 + px];
        sT[px * 68 + c] = f2bf(tanhf(v * scs[c] + shs[c]));
    }
    __syncthreads();
    unsigned int* yd = (unsigned int*)y1b;
    for (int i = t; i < 2048; i += 256) {
        int px = i >> 5, cw = i & 31;
        unsigned int lo = sT[px * 68 + cw * 2], hi = sT[px * 68 + cw * 2 + 1];
        yd[(((size_t)n << 12) + hw0 + px) * 32 + cw] = lo | (hi << 16);
    }
}

// ---------------------------------------------------------------------------
// Fused tail (round-12 version: hoisted P2 loads, m/tt-outer phase 2)
#define YPAD_ 97
__global__ __launch_bounds__(256) void k_ytail(const float* __restrict__ y2,
                                               const float2* __restrict__ part,
                                               const float* __restrict__ g,
                                               const float* __restrict__ bb,
                                               const unsigned int* __restrict__ P2,
                                               const unsigned short* __restrict__ wbp,
                                               const float* __restrict__ out_b,
                                               float* __restrict__ out) {
    __shared__ float scs[BC_], shs[BC_];
    __shared__ float cfs[BC_][32];
    __shared__ unsigned int sYh[32 * YPAD_];
    __shared__ unsigned int sYl[32 * YPAD_];

    int bid = blockIdx.x;
    int n = bid >> 7, px0 = (bid & 127) << 5;
    int t = threadIdx.x;

    int px = t & 31, cg = t >> 5;
    unsigned int u[4][9];
    {
        const unsigned int* Pb = P2 + (((size_t)n * P2CH_) << 12) + px0 + px;
        #pragma unroll
        for (int cc = 0; cc < 4; cc++) {
            int c = cg * 4 + cc;
            #pragma unroll
            for (int tp = 0; tp < 9; tp++)
                u[cc][tp] = Pb[(size_t)(tp * 32 + c) << 12];
        }
    }

    if (t < BC_) {
        float s = 0.f, s2 = 0.f;
        #pragma unroll
        for (int j = 0; j < 8; j++) { float2 p = part[t * 8 + j]; s += p.x; s2 += p.y; }
        float mu = s / (float)NHW_, var = s2 / (float)NHW_ - mu * mu;
        float sc = g[t] * rsqrtf(var + 1e-5f);
        scs[t] = sc; shs[t] = bb[t] - mu * sc;
    }
    __syncthreads();

    for (int i = t; i < BC_ * 32; i += 256) {
        int ch = i >> 5, pxx = i & 31;
        float v = y2[(((size_t)n * BC_ + ch) << 12) + px0 + pxx];
        cfs[ch][pxx] = tanhf(v * scs[ch] + shs[ch]);
    }
    __syncthreads();

    {
        float pv[4][TB_];
        #pragma unroll
        for (int cc = 0; cc < 4; cc++)
            #pragma unroll
            for (int tp = 0; tp < 9; tp++) {
                pv[cc][2 * tp]     = __uint_as_float(u[cc][tp] << 16);
                pv[cc][2 * tp + 1] = __uint_as_float(u[cc][tp] & 0xffff0000u);
            }
        float ym[4][NB_];
        #pragma unroll
        for (int cc = 0; cc < 4; cc++)
            #pragma unroll
            for (int m = 0; m < NB_; m++) ym[cc][m] = 0.f;
        #pragma unroll
        for (int m = 0; m < NB_; m++)
            #pragma unroll
            for (int tt = 0; tt < TB_; tt++) {
                float cfv = cfs[m * TB_ + tt][px];
                #pragma unroll
                for (int cc = 0; cc < 4; cc++)
                    ym[cc][m] += cfv * pv[cc][tt];
            }
        #pragma unroll
        for (int cc = 0; cc < 4; cc++) {
            int c = cg * 4 + cc;
            #pragma unroll
            for (int j = 0; j < 3; j++) {
                unsigned short h0 = f2bf(ym[cc][2 * j]);
                unsigned short h1 = f2bf(ym[cc][2 * j + 1]);
                unsigned short l0 = f2bf(ym[cc][2 * j] - bf2f(h0));
                unsigned short l1 = f2bf(ym[cc][2 * j + 1] - bf2f(h1));
                sYh[px * YPAD_ + c * 3 + j] = (unsigned int)h0 | ((unsigned int)h1 << 16);
                sYl[px * YPAD_ + c * 3 + j] = (unsigned int)l0 | ((unsigned int)l1 << 16);
            }
        }
    }
    __syncthreads();

    int lane = t & 63, wv = t >> 6;
    int q = lane >> 4, n15 = lane & 15;
    f32x4 acc[2];
    acc[0] = (f32x4){0.f, 0.f, 0.f, 0.f};
    acc[1] = (f32x4){0.f, 0.f, 0.f, 0.f};
    #pragma unroll
    for (int ks = 0; ks < 6; ks++) {
        short8 ah = *(const short8*)(wbp + (wv * 16 + n15) * DDIM_ + ks * 32 + q * 8);
        short8 al = *(const short8*)(wbp + OUT_ * DDIM_ + (wv * 16 + n15) * DDIM_ + ks * 32 + q * 8);
        #pragma unroll
        for (int nt = 0; nt < 2; nt++) {
            short8 bh = frag4(sYh + (nt * 16 + n15) * YPAD_ + ks * 16 + q * 4);
            short8 bl = frag4(sYl + (nt * 16 + n15) * YPAD_ + ks * 16 + q * 4);
            acc[nt] = __builtin_amdgcn_mfma_f32_16x16x32_bf16(ah, bh, acc[nt], 0, 0, 0);
            acc[nt] = __builtin_amdgcn_mfma_f32_16x16x32_bf16(ah, bl, acc[nt], 0, 0, 0);
            acc[nt] = __builtin_amdgcn_mfma_f32_16x16x32_bf16(al, bh, acc[nt], 0, 0, 0);
        }
    }
    #pragma unroll
    for (int nt = 0; nt < 2; nt++)
        #pragma unroll
        for (int reg = 0; reg < 4; reg++) {
            int o = wv * 16 + q * 4 + reg;
            out[(((size_t)n * OUT_ + o) << 12) + px0 + nt * 16 + n15] = acc[nt][reg] + out_b[o];
        }
}

extern "C" void kernel_launch(void* const* d_in, const int* in_sizes, int n_in,
                              void* d_out, int out_size, void* d_ws, size_t ws_size,
                              hipStream_t stream) {
    const float* x       = (const float*)d_in[0];
    const float* conv1_w = (const float*)d_in[1];
    const float* conv1_b = (const float*)d_in[2];
    const float* bn1_g   = (const float*)d_in[3];
    const float* bn1_b   = (const float*)d_in[4];
    const float* conv2_w = (const float*)d_in[5];
    const float* conv2_b = (const float*)d_in[6];
    const float* bn2_g   = (const float*)d_in[7];
    const float* bn2_b   = (const float*)d_in[8];
    const float* bases   = (const float*)d_in[9];
    const float* out_w   = (const float*)d_in[10];
    const float* out_b   = (const float*)d_in[11];
    float* out = (float*)d_out;

    float* y1  = (float*)d_ws;                       // 2,097,152 f32
    float* y2  = y1 + (size_t)N_ * INTER_ * HW_;     // 3,538,944 f32
    unsigned int* P2 = (unsigned int*)(y2 + (size_t)N_ * BC_ * HW_); // 9,437,184 dw
    unsigned short* xb  = (unsigned short*)(P2 + (size_t)N_ * P2CH_ * HW_); // 1,048,576
    unsigned short* y1b = xb + (size_t)NHW_ * C_;    // 2,097,152
    unsigned short* wb1 = y1b + (size_t)NHW_ * INTER_; // 18,432
    unsigned short* wb2 = wb1 + 9 * 64 * 32;         // 73,728
    unsigned short* wbp = wb2 + 9 * 128 * 64;        // 24,576 (hi + lo)
    float2* part1 = (float2*)(wbp + 2 * OUT_ * DDIM_); // 64*8
    float2* part2 = part1 + INTER_ * 8;              // 108*8

    k_prep<<<920, 256, 0, stream>>>(x, conv1_w, conv2_w, out_w, xb, wb1, wb2, wbp);

    k_conv3<C_, 64, 1, 64, 1><<<N_ * 64, 256, 0, stream>>>(
        xb, wb1, conv1_b, y1, INTER_);
    k_bnpart<<<INTER_ * 8, 256, 0, stream>>>(y1, part1, INTER_);
    k_bntr<<<512, 256, 0, stream>>>(y1, part1, bn1_g, bn1_b, y1b);

    k_cpv<<<2816, 256, 0, stream>>>(y1b, wb2, conv2_b, y2, x, bases, P2);
    k_bnpart<<<BC_ * 8, 256, 0, stream>>>(y2, part2, BC_);

    k_ytail<<<1024, 256, 0, stream>>>(y2, (const float2*)part2, bn2_g, bn2_b,
                                      P2, wbp, out_b, out);
}

// Round 14
// 187.542 us; speedup vs baseline: 1.1059x; 1.1059x over previous
//
#include <hip/hip_runtime.h>
#include <hip/hip_bf16.h>

#define N_ 8
#define C_ 32
#define H_ 64
#define W_ 64
#define HW_ (H_*W_)
#define NHW_ (N_*HW_)
#define INTER_ 64
#define BC_ 108
#define KS_ 7
#define K2_ (KS_*KS_)
#define NB_ 6
#define TB_ 18
#define OUT_ 64
#define DDIM_ (C_*NB_)   // 192
#define P2CH_ 288        // 9 tp-pairs * 32 c

typedef __attribute__((ext_vector_type(8))) short short8;
typedef __attribute__((ext_vector_type(4))) float f32x4;

__device__ __forceinline__ unsigned short f2bf(float f) {
    union { float f; unsigned u; } v; v.f = f;
    unsigned r = v.u + 0x7fffu + ((v.u >> 16) & 1u);
    return (unsigned short)(r >> 16);
}
__device__ __forceinline__ float bf2f(unsigned short h) {
    return __uint_as_float((unsigned int)h << 16);
}

__device__ __forceinline__ short8 frag4(const unsigned int* p) {
    union { unsigned int u[4]; short8 s; } v;
    v.u[0] = p[0]; v.u[1] = p[1]; v.u[2] = p[2]; v.u[3] = p[3];
    return v.s;
}

__inline__ __device__ float wave_reduce_sum(float v) {
    #pragma unroll
    for (int off = 32; off > 0; off >>= 1) v += __shfl_down(v, off);
    return v;
}

// pconv pass over a tp-subrange: caps live accumulators at NTP*8 (+12 rw)
// so the branch stays under ~70 VGPR (no scratch spills).
template<int TP0, int NTP>
__device__ __forceinline__ void pconv_pass(const float (*sx)[44],
                                           const float* __restrict__ bases,
                                           unsigned int* __restrict__ P2,
                                           int n, int c, int r0, int rb, int lane) {
    float a0[NTP][4], a1[NTP][4];
    #pragma unroll
    for (int tp = 0; tp < NTP; tp++)
        #pragma unroll
        for (int rr = 0; rr < 4; rr++) { a0[tp][rr] = 0.f; a1[tp][rr] = 0.f; }

    #pragma unroll 1
    for (int kx = 0; kx < 7; kx++) {
        float rw[12];
        const float* sp = &sx[lane + kx][rb];
        #pragma unroll
        for (int qq = 0; qq < 3; qq++) {
            float4 r4 = *(const float4*)(sp + qq * 4);
            rw[qq * 4 + 0] = r4.x; rw[qq * 4 + 1] = r4.y;
            rw[qq * 4 + 2] = r4.z; rw[qq * 4 + 3] = r4.w;
        }
        #pragma unroll
        for (int tp = 0; tp < NTP; tp++) {
            #pragma unroll
            for (int ky = 0; ky < 7; ky++) {
                float w0  = bases[(2 * (TP0 + tp)) * K2_ + ky * 7 + kx];
                float w1v = bases[(2 * (TP0 + tp) + 1) * K2_ + ky * 7 + kx];
                #pragma unroll
                for (int rr = 0; rr < 4; rr++) {
                    float xv = rw[rr + ky];
                    a0[tp][rr] += xv * w0;
                    a1[tp][rr] += xv * w1v;
                }
            }
        }
    }

    #pragma unroll
    for (int tp = 0; tp < NTP; tp++)
        #pragma unroll
        for (int rr = 0; rr < 4; rr++) {
            int gr = r0 + rb + rr;
            unsigned int pk = (unsigned int)f2bf(a0[tp][rr]) |
                              ((unsigned int)f2bf(a1[tp][rr]) << 16);
            P2[(((size_t)n * P2CH_ + (TP0 + tp) * 32 + c) << 12) + (gr << 6) + lane] = pk;
        }
}

// ---------------------------------------------------------------------------
// k_front: horizontal fusion of (pconv | prep).
//  bid <  1024 : pconv -> P2 (reads raw x, bases only)
//  1024..1943  : prep (x->xb NHWC bf16, conv weights, out_w hi/lo)
__global__ __launch_bounds__(256) void k_front(const float* __restrict__ x,
                                               const float* __restrict__ bases,
                                               const float* __restrict__ w1,
                                               const float* __restrict__ w2,
                                               const float* __restrict__ ow,
                                               unsigned short* __restrict__ xb,
                                               unsigned short* __restrict__ wb1,
                                               unsigned short* __restrict__ wb2,
                                               unsigned short* __restrict__ wbp,
                                               unsigned int* __restrict__ P2) {
    __shared__ __align__(16) char smem[70 * 44 * 4];
    int bid = blockIdx.x, t = threadIdx.x;

    if (bid < 1024) {
        // ----- pconv: P2[n][tp*32+c][h][w] packs bases(2tp,2tp+1) 7x7-corr
        float (*sx)[44] = (float(*)[44])smem;
        int rq = bid & 3;
        int c  = (bid >> 2) & 31;
        int n  = bid >> 7;
        int lane = t & 63, wv = t >> 6;
        int r0 = rq << 4;

        const float* xc = x + (((size_t)n * C_ + c) << 12);
        #pragma unroll
        for (int j = 0; j < 6; j++) {
            int p = wv + 4 * j;
            if (p < 22) {
                int grow = r0 - 3 + p;
                bool rowok = (grow >= 0 && grow < H_);
                int wx = lane - 3;
                float v = 0.f;
                if (rowok && wx >= 0) v = xc[(grow << 6) + wx];
                sx[lane][p] = v;
                if (lane < 6) {
                    int wx2 = 61 + lane;
                    float v2 = 0.f;
                    if (rowok && wx2 < W_) v2 = xc[(grow << 6) + wx2];
                    sx[64 + lane][p] = v2;
                }
            }
        }
        __syncthreads();

        int rb = wv * 4;
        pconv_pass<0, 5>(sx, bases, P2, n, c, r0, rb, lane);
        pconv_pass<5, 4>(sx, bases, P2, n, c, r0, rb, lane);
    } else {
        int pbid = bid - 1024;   // 0..919
        if (pbid < 512) {
            unsigned short* sT = (unsigned short*)smem;   // 64*36 ushort
            int n = pbid >> 6, hw0 = (pbid << 6) & 4095;
            for (int i = t; i < 2048; i += 256) {
                int c = i >> 6, px = i & 63;
                float v = x[(((size_t)n * C_ + c) << 12) + hw0 + px];
                sT[px * 36 + c] = f2bf(v);
            }
            __syncthreads();
            unsigned int* xd = (unsigned int*)xb;
            for (int i = t; i < 1024; i += 256) {
                int px = i >> 4, cw = i & 15;
                unsigned int lo = sT[px * 36 + cw * 2], hi = sT[px * 36 + cw * 2 + 1];
                xd[(((size_t)n << 12) + hw0 + px) * 16 + cw] = lo | (hi << 16);
            }
        } else if (pbid < 584) {
            int i = (pbid - 512) * 256 + t;       // < 18432 = 9*64*32
            int ci = i & 31, co = (i >> 5) & 63, s = i >> 11;
            wb1[i] = f2bf(w1[((co << 5) + ci) * 9 + s]);
        } else if (pbid < 872) {
            int i = (pbid - 584) * 256 + t;       // < 73728 = 9*128*64
            int ci = i & 63, co = (i >> 6) & 127, s = i >> 13;
            unsigned short v = 0;
            if (co < BC_) v = f2bf(w2[((co << 6) + ci) * 9 + s]);
            wb2[i] = v;
        } else {
            int i = (pbid - 872) * 256 + t;       // < 12288 = 64*192
            if (i < OUT_ * DDIM_) {
                float v = ow[i];
                unsigned short hi = f2bf(v);
                wbp[i] = hi;
                wbp[OUT_ * DDIM_ + i] = f2bf(v - bf2f(hi));
            }
        }
    }
}

// ---------------------------------------------------------------------------
// MFMA conv3x3 (pad=1), stage-once (all 9 shifts' weights + x tile, 1 barrier)
template<int CIN, int COG, int ROWS, int WPAD, int NCOQ>
__global__ __launch_bounds__(256) void k_conv3(const unsigned short* __restrict__ xb,
                                               const unsigned short* __restrict__ wb,
                                               const float* __restrict__ bias,
                                               float* __restrict__ y,
                                               int COUT_real) {
    constexpr int CPAD = CIN + 8;
    constexpr int NSLC = (ROWS + 2) * 66;
    constexpr int MT = COG / 16;
    constexpr int NTW = ROWS;
    constexpr int KSTEPS = CIN / 32;
    __shared__ unsigned short sx[NSLC * CPAD];
    __shared__ unsigned short sw[9 * COG * CPAD];

    int bid = blockIdx.x;
    int coq = bid % NCOQ;
    int rp = (bid / NCOQ) % (H_ / ROWS);
    int n = bid / (NCOQ * (H_ / ROWS));
    int h0 = rp * ROWS;
    int co0 = coq * COG;
    int t = threadIdx.x;
    int lane = t & 63, wv = t >> 6;
    int q = lane >> 4, n15 = lane & 15;

    {
        const unsigned int* xg = (const unsigned int*)xb + (size_t)n * HW_ * (CIN / 2);
        unsigned int* sxd = (unsigned int*)sx;
        constexpr int DW = CIN / 2;
        constexpr int DWPT = DW / 8;
        int part = t & 7;
        for (int sl = (t >> 3); sl < NSLC; sl += 32) {
            int r = sl / 66, col = sl % 66;
            int hh = h0 - 1 + r, ww = col - 1;
            unsigned int v[DWPT];
            #pragma unroll
            for (int i = 0; i < DWPT; i++) v[i] = 0;
            if (hh >= 0 && hh < H_ && ww >= 0 && ww < W_) {
                const unsigned int* gp = xg + (size_t)(hh * W_ + ww) * DW + part * DWPT;
                #pragma unroll
                for (int i = 0; i < DWPT; i++) v[i] = gp[i];
            }
            unsigned int* d = sxd + sl * (CPAD / 2) + part * DWPT;
            #pragma unroll
            for (int i = 0; i < DWPT; i++) d[i] = v[i];
        }
    }
    {
        const unsigned int* wg = (const unsigned int*)wb;
        unsigned int* swd = (unsigned int*)sw;
        constexpr int TOT = 9 * COG * (CIN / 2);
        for (int e = t; e < TOT; e += 256) {
            int s_co = e / (CIN / 2), cw = e % (CIN / 2);
            int s = s_co / COG, co = s_co % COG;
            swd[s_co * (CPAD / 2) + cw] = wg[((size_t)s * WPAD + co0 + co) * (CIN / 2) + cw];
        }
    }
    __syncthreads();

    f32x4 acc[NTW][MT];
    #pragma unroll
    for (int a = 0; a < NTW; a++)
        #pragma unroll
        for (int m = 0; m < MT; m++) acc[a][m] = (f32x4){0.f, 0.f, 0.f, 0.f};

    #pragma unroll
    for (int s = 0; s < 9; s++) {
        int dy = s / 3, dx = s % 3;
        #pragma unroll
        for (int kc = 0; kc < KSTEPS; kc++) {
            int ci0 = kc * 32;
            short8 bfr[NTW];
            #pragma unroll
            for (int ntl = 0; ntl < NTW; ntl++) {
                int nt = wv * NTW + ntl;
                int r_out = nt >> 2, col0 = (nt & 3) * 16;
                bfr[ntl] = *(const short8*)(sx + ((r_out + dy) * 66 + col0 + n15 + dx) * CPAD + ci0 + q * 8);
            }
            #pragma unroll
            for (int mt = 0; mt < MT; mt++) {
                short8 afr = *(const short8*)(sw + ((s * COG) + mt * 16 + n15) * CPAD + ci0 + q * 8);
                #pragma unroll
                for (int ntl = 0; ntl < NTW; ntl++)
                    acc[ntl][mt] = __builtin_amdgcn_mfma_f32_16x16x32_bf16(afr, bfr[ntl], acc[ntl][mt], 0, 0, 0);
            }
        }
    }

    #pragma unroll
    for (int ntl = 0; ntl < NTW; ntl++) {
        int nt = wv * NTW + ntl;
        int h = h0 + (nt >> 2), wcol = (nt & 3) * 16 + n15;
        #pragma unroll
        for (int mt = 0; mt < MT; mt++) {
            #pragma unroll
            for (int reg = 0; reg < 4; reg++) {
                int co = co0 + mt * 16 + q * 4 + reg;
                if (co < COUT_real)
                    y[(((size_t)n * COUT_real + co) << 12) + h * W_ + wcol] = acc[ntl][mt][reg] + bias[co];
            }
        }
    }
}

// ---------------------------------------------------------------------------
__global__ __launch_bounds__(256) void k_bnpart(const float* __restrict__ y,
                                                float2* __restrict__ part, int Cout) {
    int bid = blockIdx.x;
    int c = bid >> 3, n = bid & 7;
    int t = threadIdx.x;
    const float* p = y + (((size_t)n * Cout + c) << 12) + t * 16;
    float s = 0.f, s2 = 0.f;
    #pragma unroll
    for (int j = 0; j < 4; j++) {
        float4 v = *(const float4*)(p + j * 4);
        s += v.x + v.y + v.z + v.w;
        s2 += v.x * v.x + v.y * v.y + v.z * v.z + v.w * v.w;
    }
    s = wave_reduce_sum(s);
    s2 = wave_reduce_sum(s2);
    __shared__ float sm[8];
    int wid = t >> 6, lane = t & 63;
    if (lane == 0) { sm[wid] = s; sm[4 + wid] = s2; }
    __syncthreads();
    if (t == 0) {
        float2 r;
        r.x = sm[0] + sm[1] + sm[2] + sm[3];
        r.y = sm[4] + sm[5] + sm[6] + sm[7];
        part[c * 8 + n] = r;
    }
}

// ---------------------------------------------------------------------------
// y1 NCHW f32 -> tanh(bn) -> y1b NHWC bf16
__global__ __launch_bounds__(256) void k_bntr(const float* __restrict__ y1,
                                              const float2* __restrict__ part,
                                              const float* __restrict__ g,
                                              const float* __restrict__ bb,
                                              unsigned short* __restrict__ y1b) {
    __shared__ unsigned short sT[64 * 68];
    __shared__ float scs[INTER_], shs[INTER_];
    int bid = blockIdx.x, t = threadIdx.x;
    int n = bid >> 6, hw0 = (bid << 6) & 4095;
    if (t < INTER_) {
        float s = 0.f, s2 = 0.f;
        #pragma unroll
        for (int j = 0; j < 8; j++) { float2 p = part[t * 8 + j]; s += p.x; s2 += p.y; }
        float mu = s / (float)NHW_, var = s2 / (float)NHW_ - mu * mu;
        float sc = g[t] * rsqrtf(var + 1e-5f);
        scs[t] = sc; shs[t] = bb[t] - mu * sc;
    }
    __syncthreads();
    for (int i = t; i < 4096; i += 256) {
        int c = i >> 6, px = i & 63;
        float v = y1[(((size_t)n * INTER_ + c) << 12) + hw0 + px];
        sT[px * 68 + c] = f2bf(tanhf(v * scs[c] + shs[c]));
    }
    __syncthreads();
    unsigned int* yd = (unsigned int*)y1b;
    for (int i = t; i < 2048; i += 256) {
        int px = i >> 5, cw = i & 31;
        unsigned int lo = sT[px * 68 + cw * 2], hi = sT[px * 68 + cw * 2 + 1];
        yd[(((size_t)n << 12) + hw0 + px) * 32 + cw] = lo | (hi << 16);
    }
}

// ---------------------------------------------------------------------------
// Fused tail: hoisted P2 loads, m/tt-outer phase 2, split-bf16 MFMA proj.
#define YPAD_ 97
__global__ __launch_bounds__(256) void k_ytail(const float* __restrict__ y2,
                                               const float2* __restrict__ part,
                                               const float* __restrict__ g,
                                               const float* __restrict__ bb,
                                               const unsigned int* __restrict__ P2,
                                               const unsigned short* __restrict__ wbp,
                                               const float* __restrict__ out_b,
                                               float* __restrict__ out) {
    __shared__ float scs[BC_], shs[BC_];
    __shared__ float cfs[BC_][32];
    __shared__ unsigned int sYh[32 * YPAD_];
    __shared__ unsigned int sYl[32 * YPAD_];

    int bid = blockIdx.x;
    int n = bid >> 7, px0 = (bid & 127) << 5;
    int t = threadIdx.x;

    int px = t & 31, cg = t >> 5;
    unsigned int u[4][9];
    {
        const unsigned int* Pb = P2 + (((size_t)n * P2CH_) << 12) + px0 + px;
        #pragma unroll
        for (int cc = 0; cc < 4; cc++) {
            int c = cg * 4 + cc;
            #pragma unroll
            for (int tp = 0; tp < 9; tp++)
                u[cc][tp] = Pb[(size_t)(tp * 32 + c) << 12];
        }
    }

    if (t < BC_) {
        float s = 0.f, s2 = 0.f;
        #pragma unroll
        for (int j = 0; j < 8; j++) { float2 p = part[t * 8 + j]; s += p.x; s2 += p.y; }
        float mu = s / (float)NHW_, var = s2 / (float)NHW_ - mu * mu;
        float sc = g[t] * rsqrtf(var + 1e-5f);
        scs[t] = sc; shs[t] = bb[t] - mu * sc;
    }
    __syncthreads();

    for (int i = t; i < BC_ * 32; i += 256) {
        int ch = i >> 5, pxx = i & 31;
        float v = y2[(((size_t)n * BC_ + ch) << 12) + px0 + pxx];
        cfs[ch][pxx] = tanhf(v * scs[ch] + shs[ch]);
    }
    __syncthreads();

    {
        float pv[4][TB_];
        #pragma unroll
        for (int cc = 0; cc < 4; cc++)
            #pragma unroll
            for (int tp = 0; tp < 9; tp++) {
                pv[cc][2 * tp]     = __uint_as_float(u[cc][tp] << 16);
                pv[cc][2 * tp + 1] = __uint_as_float(u[cc][tp] & 0xffff0000u);
            }
        float ym[4][NB_];
        #pragma unroll
        for (int cc = 0; cc < 4; cc++)
            #pragma unroll
            for (int m = 0; m < NB_; m++) ym[cc][m] = 0.f;
        #pragma unroll
        for (int m = 0; m < NB_; m++)
            #pragma unroll
            for (int tt = 0; tt < TB_; tt++) {
                float cfv = cfs[m * TB_ + tt][px];
                #pragma unroll
                for (int cc = 0; cc < 4; cc++)
                    ym[cc][m] += cfv * pv[cc][tt];
            }
        #pragma unroll
        for (int cc = 0; cc < 4; cc++) {
            int c = cg * 4 + cc;
            #pragma unroll
            for (int j = 0; j < 3; j++) {
                unsigned short h0 = f2bf(ym[cc][2 * j]);
                unsigned short h1 = f2bf(ym[cc][2 * j + 1]);
                unsigned short l0 = f2bf(ym[cc][2 * j] - bf2f(h0));
                unsigned short l1 = f2bf(ym[cc][2 * j + 1] - bf2f(h1));
                sYh[px * YPAD_ + c * 3 + j] = (unsigned int)h0 | ((unsigned int)h1 << 16);
                sYl[px * YPAD_ + c * 3 + j] = (unsigned int)l0 | ((unsigned int)l1 << 16);
            }
        }
    }
    __syncthreads();

    int lane = t & 63, wv = t >> 6;
    int q = lane >> 4, n15 = lane & 15;
    f32x4 acc[2];
    acc[0] = (f32x4){0.f, 0.f, 0.f, 0.f};
    acc[1] = (f32x4){0.f, 0.f, 0.f, 0.f};
    #pragma unroll
    for (int ks = 0; ks < 6; ks++) {
        short8 ah = *(const short8*)(wbp + (wv * 16 + n15) * DDIM_ + ks * 32 + q * 8);
        short8 al = *(const short8*)(wbp + OUT_ * DDIM_ + (wv * 16 + n15) * DDIM_ + ks * 32 + q * 8);
        #pragma unroll
        for (int nt = 0; nt < 2; nt++) {
            short8 bh = frag4(sYh + (nt * 16 + n15) * YPAD_ + ks * 16 + q * 4);
            short8 bl = frag4(sYl + (nt * 16 + n15) * YPAD_ + ks * 16 + q * 4);
            acc[nt] = __builtin_amdgcn_mfma_f32_16x16x32_bf16(ah, bh, acc[nt], 0, 0, 0);
            acc[nt] = __builtin_amdgcn_mfma_f32_16x16x32_bf16(ah, bl, acc[nt], 0, 0, 0);
            acc[nt] = __builtin_amdgcn_mfma_f32_16x16x32_bf16(al, bh, acc[nt], 0, 0, 0);
        }
    }
    #pragma unroll
    for (int nt = 0; nt < 2; nt++)
        #pragma unroll
        for (int reg = 0; reg < 4; reg++) {
            int o = wv * 16 + q * 4 + reg;
            out[(((size_t)n * OUT_ + o) << 12) + px0 + nt * 16 + n15] = acc[nt][reg] + out_b[o];
        }
}

extern "C" void kernel_launch(void* const* d_in, const int* in_sizes, int n_in,
                              void* d_out, int out_size, void* d_ws, size_t ws_size,
                              hipStream_t stream) {
    const float* x       = (const float*)d_in[0];
    const float* conv1_w = (const float*)d_in[1];
    const float* conv1_b = (const float*)d_in[2];
    const float* bn1_g   = (const float*)d_in[3];
    const float* bn1_b   = (const float*)d_in[4];
    const float* conv2_w = (const float*)d_in[5];
    const float* conv2_b = (const float*)d_in[6];
    const float* bn2_g   = (const float*)d_in[7];
    const float* bn2_b   = (const float*)d_in[8];
    const float* bases   = (const float*)d_in[9];
    const float* out_w   = (const float*)d_in[10];
    const float* out_b   = (const float*)d_in[11];
    float* out = (float*)d_out;

    float* y1  = (float*)d_ws;                       // 2,097,152 f32
    float* y2  = y1 + (size_t)N_ * INTER_ * HW_;     // 3,538,944 f32
    unsigned int* P2 = (unsigned int*)(y2 + (size_t)N_ * BC_ * HW_); // 9,437,184 dw
    unsigned short* xb  = (unsigned short*)(P2 + (size_t)N_ * P2CH_ * HW_); // 1,048,576
    unsigned short* y1b = xb + (size_t)NHW_ * C_;    // 2,097,152
    unsigned short* wb1 = y1b + (size_t)NHW_ * INTER_; // 18,432
    unsigned short* wb2 = wb1 + 9 * 64 * 32;         // 73,728
    unsigned short* wbp = wb2 + 9 * 128 * 64;        // 24,576 (hi + lo)
    float2* part1 = (float2*)(wbp + 2 * OUT_ * DDIM_); // 64*8
    float2* part2 = part1 + INTER_ * 8;              // 108*8

    k_front<<<1944, 256, 0, stream>>>(x, bases, conv1_w, conv2_w, out_w,
                                      xb, wb1, wb2, wbp, P2);

    k_conv3<C_, 64, 1, 64, 1><<<N_ * 64, 256, 0, stream>>>(
        xb, wb1, conv1_b, y1, INTER_);
    k_bnpart<<<INTER_ * 8, 256, 0, stream>>>(y1, part1, INTER_);
    k_bntr<<<512, 256, 0, stream>>>(y1, part1, bn1_g, bn1_b, y1b);

    k_conv3<INTER_, 16, 2, 128, 7><<<N_ * 32 * 7, 256, 0, stream>>>(
        y1b, wb2, conv2_b, y2, BC_);
    k_bnpart<<<BC_ * 8, 256, 0, stream>>>(y2, part2, BC_);

    k_ytail<<<1024, 256, 0, stream>>>(y2, (const float2*)part2, bn2_g, bn2_b,
                                      P2, wbp, out_b, out);
}

// Round 15
// 178.154 us; speedup vs baseline: 1.1642x; 1.0527x over previous
//
#include <hip/hip_runtime.h>
#include <hip/hip_bf16.h>

#define N_ 8
#define C_ 32
#define H_ 64
#define W_ 64
#define HW_ (H_*W_)
#define NHW_ (N_*HW_)
#define INTER_ 64
#define BC_ 108
#define KS_ 7
#define K2_ (KS_*KS_)
#define NB_ 6
#define TB_ 18
#define OUT_ 64
#define DDIM_ (C_*NB_)   // 192
#define P2CH_ 288        // 9 tp-pairs * 32 c

typedef __attribute__((ext_vector_type(8))) short short8;
typedef __attribute__((ext_vector_type(4))) float f32x4;
typedef __attribute__((ext_vector_type(2))) float f32x2;

__device__ __forceinline__ unsigned short f2bf(float f) {
    union { float f; unsigned u; } v; v.f = f;
    unsigned r = v.u + 0x7fffu + ((v.u >> 16) & 1u);
    return (unsigned short)(r >> 16);
}
__device__ __forceinline__ float bf2f(unsigned short h) {
    return __uint_as_float((unsigned int)h << 16);
}

__device__ __forceinline__ short8 frag4(const unsigned int* p) {
    union { unsigned int u[4]; short8 s; } v;
    v.u[0] = p[0]; v.u[1] = p[1]; v.u[2] = p[2]; v.u[3] = p[3];
    return v.s;
}

__inline__ __device__ float wave_reduce_sum(float v) {
    #pragma unroll
    for (int off = 32; off > 0; off >>= 1) v += __shfl_down(v, off);
    return v;
}

// pconv pass over a tp-subrange. Accumulators are (a0,a1) f32x2 pairs so the
// inner op is v_pk_fma_f32 (packed fp32, 2x scalar rate): same xv (splat,
// op_sel-foldable), independent weight pair.
template<int TP0, int NTP>
__device__ __forceinline__ void pconv_pass(const float (*sx)[44],
                                           const float* __restrict__ bases,
                                           unsigned int* __restrict__ P2,
                                           int n, int c, int r0, int rb, int lane) {
    f32x2 av[NTP][4];
    #pragma unroll
    for (int tp = 0; tp < NTP; tp++)
        #pragma unroll
        for (int rr = 0; rr < 4; rr++) av[tp][rr] = (f32x2){0.f, 0.f};

    #pragma unroll 1
    for (int kx = 0; kx < 7; kx++) {
        float rw[12];
        const float* sp = &sx[lane + kx][rb];
        #pragma unroll
        for (int qq = 0; qq < 3; qq++) {
            float4 r4 = *(const float4*)(sp + qq * 4);
            rw[qq * 4 + 0] = r4.x; rw[qq * 4 + 1] = r4.y;
            rw[qq * 4 + 2] = r4.z; rw[qq * 4 + 3] = r4.w;
        }
        #pragma unroll
        for (int tp = 0; tp < NTP; tp++) {
            #pragma unroll
            for (int ky = 0; ky < 7; ky++) {
                f32x2 w2;
                w2.x = bases[(2 * (TP0 + tp)) * K2_ + ky * 7 + kx];
                w2.y = bases[(2 * (TP0 + tp) + 1) * K2_ + ky * 7 + kx];
                #pragma unroll
                for (int rr = 0; rr < 4; rr++) {
                    float xv = rw[rr + ky];
                    f32x2 xv2 = (f32x2){xv, xv};
                    av[tp][rr] += xv2 * w2;
                }
            }
        }
    }

    #pragma unroll
    for (int tp = 0; tp < NTP; tp++)
        #pragma unroll
        for (int rr = 0; rr < 4; rr++) {
            int gr = r0 + rb + rr;
            unsigned int pk = (unsigned int)f2bf(av[tp][rr].x) |
                              ((unsigned int)f2bf(av[tp][rr].y) << 16);
            P2[(((size_t)n * P2CH_ + (TP0 + tp) * 32 + c) << 12) + (gr << 6) + lane] = pk;
        }
}

// ---------------------------------------------------------------------------
// k_front: horizontal fusion of (pconv | prep).
__global__ __launch_bounds__(256) void k_front(const float* __restrict__ x,
                                               const float* __restrict__ bases,
                                               const float* __restrict__ w1,
                                               const float* __restrict__ w2,
                                               const float* __restrict__ ow,
                                               unsigned short* __restrict__ xb,
                                               unsigned short* __restrict__ wb1,
                                               unsigned short* __restrict__ wb2,
                                               unsigned short* __restrict__ wbp,
                                               unsigned int* __restrict__ P2) {
    __shared__ __align__(16) char smem[70 * 44 * 4];
    int bid = blockIdx.x, t = threadIdx.x;

    if (bid < 1024) {
        float (*sx)[44] = (float(*)[44])smem;
        int rq = bid & 3;
        int c  = (bid >> 2) & 31;
        int n  = bid >> 7;
        int lane = t & 63, wv = t >> 6;
        int r0 = rq << 4;

        const float* xc = x + (((size_t)n * C_ + c) << 12);
        #pragma unroll
        for (int j = 0; j < 6; j++) {
            int p = wv + 4 * j;
            if (p < 22) {
                int grow = r0 - 3 + p;
                bool rowok = (grow >= 0 && grow < H_);
                int wx = lane - 3;
                float v = 0.f;
                if (rowok && wx >= 0) v = xc[(grow << 6) + wx];
                sx[lane][p] = v;
                if (lane < 6) {
                    int wx2 = 61 + lane;
                    float v2 = 0.f;
                    if (rowok && wx2 < W_) v2 = xc[(grow << 6) + wx2];
                    sx[64 + lane][p] = v2;
                }
            }
        }
        __syncthreads();

        int rb = wv * 4;
        pconv_pass<0, 5>(sx, bases, P2, n, c, r0, rb, lane);
        pconv_pass<5, 4>(sx, bases, P2, n, c, r0, rb, lane);
    } else {
        int pbid = bid - 1024;   // 0..919
        if (pbid < 512) {
            unsigned short* sT = (unsigned short*)smem;   // 64*36 ushort
            int n = pbid >> 6, hw0 = (pbid << 6) & 4095;
            for (int i = t; i < 2048; i += 256) {
                int c = i >> 6, px = i & 63;
                float v = x[(((size_t)n * C_ + c) << 12) + hw0 + px];
                sT[px * 36 + c] = f2bf(v);
            }
            __syncthreads();
            unsigned int* xd = (unsigned int*)xb;
            for (int i = t; i < 1024; i += 256) {
                int px = i >> 4, cw = i & 15;
                unsigned int lo = sT[px * 36 + cw * 2], hi = sT[px * 36 + cw * 2 + 1];
                xd[(((size_t)n << 12) + hw0 + px) * 16 + cw] = lo | (hi << 16);
            }
        } else if (pbid < 584) {
            int i = (pbid - 512) * 256 + t;       // < 18432 = 9*64*32
            int ci = i & 31, co = (i >> 5) & 63, s = i >> 11;
            wb1[i] = f2bf(w1[((co << 5) + ci) * 9 + s]);
        } else if (pbid < 872) {
            int i = (pbid - 584) * 256 + t;       // < 73728 = 9*128*64
            int ci = i & 63, co = (i >> 6) & 127, s = i >> 13;
            unsigned short v = 0;
            if (co < BC_) v = f2bf(w2[((co << 6) + ci) * 9 + s]);
            wb2[i] = v;
        } else {
            int i = (pbid - 872) * 256 + t;       // < 12288 = 64*192
            if (i < OUT_ * DDIM_) {
                float v = ow[i];
                unsigned short hi = f2bf(v);
                wbp[i] = hi;
                wbp[OUT_ * DDIM_ + i] = f2bf(v - bf2f(hi));
            }
        }
    }
}

// ---------------------------------------------------------------------------
// MFMA conv3x3 (pad=1), stage-once (all 9 shifts' weights + x tile, 1 barrier)
template<int CIN, int COG, int ROWS, int WPAD, int NCOQ>
__global__ __launch_bounds__(256) void k_conv3(const unsigned short* __restrict__ xb,
                                               const unsigned short* __restrict__ wb,
                                               const float* __restrict__ bias,
                                               float* __restrict__ y,
                                               int COUT_real) {
    constexpr int CPAD = CIN + 8;
    constexpr int NSLC = (ROWS + 2) * 66;
    constexpr int MT = COG / 16;
    constexpr int NTW = ROWS;
    constexpr int KSTEPS = CIN / 32;
    __shared__ unsigned short sx[NSLC * CPAD];
    __shared__ unsigned short sw[9 * COG * CPAD];

    int bid = blockIdx.x;
    int coq = bid % NCOQ;
    int rp = (bid / NCOQ) % (H_ / ROWS);
    int n = bid / (NCOQ * (H_ / ROWS));
    int h0 = rp * ROWS;
    int co0 = coq * COG;
    int t = threadIdx.x;
    int lane = t & 63, wv = t >> 6;
    int q = lane >> 4, n15 = lane & 15;

    {
        const unsigned int* xg = (const unsigned int*)xb + (size_t)n * HW_ * (CIN / 2);
        unsigned int* sxd = (unsigned int*)sx;
        constexpr int DW = CIN / 2;
        constexpr int DWPT = DW / 8;
        int part = t & 7;
        for (int sl = (t >> 3); sl < NSLC; sl += 32) {
            int r = sl / 66, col = sl % 66;
            int hh = h0 - 1 + r, ww = col - 1;
            unsigned int v[DWPT];
            #pragma unroll
            for (int i = 0; i < DWPT; i++) v[i] = 0;
            if (hh >= 0 && hh < H_ && ww >= 0 && ww < W_) {
                const unsigned int* gp = xg + (size_t)(hh * W_ + ww) * DW + part * DWPT;
                #pragma unroll
                for (int i = 0; i < DWPT; i++) v[i] = gp[i];
            }
            unsigned int* d = sxd + sl * (CPAD / 2) + part * DWPT;
            #pragma unroll
            for (int i = 0; i < DWPT; i++) d[i] = v[i];
        }
    }
    {
        const unsigned int* wg = (const unsigned int*)wb;
        unsigned int* swd = (unsigned int*)sw;
        constexpr int TOT = 9 * COG * (CIN / 2);
        for (int e = t; e < TOT; e += 256) {
            int s_co = e / (CIN / 2), cw = e % (CIN / 2);
            int s = s_co / COG, co = s_co % COG;
            swd[s_co * (CPAD / 2) + cw] = wg[((size_t)s * WPAD + co0 + co) * (CIN / 2) + cw];
        }
    }
    __syncthreads();

    f32x4 acc[NTW][MT];
    #pragma unroll
    for (int a = 0; a < NTW; a++)
        #pragma unroll
        for (int m = 0; m < MT; m++) acc[a][m] = (f32x4){0.f, 0.f, 0.f, 0.f};

    #pragma unroll
    for (int s = 0; s < 9; s++) {
        int dy = s / 3, dx = s % 3;
        #pragma unroll
        for (int kc = 0; kc < KSTEPS; kc++) {
            int ci0 = kc * 32;
            short8 bfr[NTW];
            #pragma unroll
            for (int ntl = 0; ntl < NTW; ntl++) {
                int nt = wv * NTW + ntl;
                int r_out = nt >> 2, col0 = (nt & 3) * 16;
                bfr[ntl] = *(const short8*)(sx + ((r_out + dy) * 66 + col0 + n15 + dx) * CPAD + ci0 + q * 8);
            }
            #pragma unroll
            for (int mt = 0; mt < MT; mt++) {
                short8 afr = *(const short8*)(sw + ((s * COG) + mt * 16 + n15) * CPAD + ci0 + q * 8);
                #pragma unroll
                for (int ntl = 0; ntl < NTW; ntl++)
                    acc[ntl][mt] = __builtin_amdgcn_mfma_f32_16x16x32_bf16(afr, bfr[ntl], acc[ntl][mt], 0, 0, 0);
            }
        }
    }

    #pragma unroll
    for (int ntl = 0; ntl < NTW; ntl++) {
        int nt = wv * NTW + ntl;
        int h = h0 + (nt >> 2), wcol = (nt & 3) * 16 + n15;
        #pragma unroll
        for (int mt = 0; mt < MT; mt++) {
            #pragma unroll
            for (int reg = 0; reg < 4; reg++) {
                int co = co0 + mt * 16 + q * 4 + reg;
                if (co < COUT_real)
                    y[(((size_t)n * COUT_real + co) << 12) + h * W_ + wcol] = acc[ntl][mt][reg] + bias[co];
            }
        }
    }
}

// ---------------------------------------------------------------------------
__global__ __launch_bounds__(256) void k_bnpart(const float* __restrict__ y,
                                                float2* __restrict__ part, int Cout) {
    int bid = blockIdx.x;
    int c = bid >> 3, n = bid & 7;
    int t = threadIdx.x;
    const float* p = y + (((size_t)n * Cout + c) << 12) + t * 16;
    float s = 0.f, s2 = 0.f;
    #pragma unroll
    for (int j = 0; j < 4; j++) {
        float4 v = *(const float4*)(p + j * 4);
        s += v.x + v.y + v.z + v.w;
        s2 += v.x * v.x + v.y * v.y + v.z * v.z + v.w * v.w;
    }
    s = wave_reduce_sum(s);
    s2 = wave_reduce_sum(s2);
    __shared__ float sm[8];
    int wid = t >> 6, lane = t & 63;
    if (lane == 0) { sm[wid] = s; sm[4 + wid] = s2; }
    __syncthreads();
    if (t == 0) {
        float2 r;
        r.x = sm[0] + sm[1] + sm[2] + sm[3];
        r.y = sm[4] + sm[5] + sm[6] + sm[7];
        part[c * 8 + n] = r;
    }
}

// ---------------------------------------------------------------------------
// y1 NCHW f32 -> tanh(bn) -> y1b NHWC bf16
__global__ __launch_bounds__(256) void k_bntr(const float* __restrict__ y1,
                                              const float2* __restrict__ part,
                                              const float* __restrict__ g,
                                              const float* __restrict__ bb,
                                              unsigned short* __restrict__ y1b) {
    __shared__ unsigned short sT[64 * 68];
    __shared__ float scs[INTER_], shs[INTER_];
    int bid = blockIdx.x, t = threadIdx.x;
    int n = bid >> 6, hw0 = (bid << 6) & 4095;
    if (t < INTER_) {
        float s = 0.f, s2 = 0.f;
        #pragma unroll
        for (int j = 0; j < 8; j++) { float2 p = part[t * 8 + j]; s += p.x; s2 += p.y; }
        float mu = s / (float)NHW_, var = s2 / (float)NHW_ - mu * mu;
        float sc = g[t] * rsqrtf(var + 1e-5f);
        scs[t] = sc; shs[t] = bb[t] - mu * sc;
    }
    __syncthreads();
    for (int i = t; i < 4096; i += 256) {
        int c = i >> 6, px = i & 63;
        float v = y1[(((size_t)n * INTER_ + c) << 12) + hw0 + px];
        sT[px * 68 + c] = f2bf(tanhf(v * scs[c] + shs[c]));
    }
    __syncthreads();
    unsigned int* yd = (unsigned int*)y1b;
    for (int i = t; i < 2048; i += 256) {
        int px = i >> 5, cw = i & 31;
        unsigned int lo = sT[px * 68 + cw * 2], hi = sT[px * 68 + cw * 2 + 1];
        yd[(((size_t)n << 12) + hw0 + px) * 32 + cw] = lo | (hi << 16);
    }
}

// ---------------------------------------------------------------------------
// Fused tail: hoisted P2 loads, packed-fp32 phase 2, split-bf16 MFMA proj.
#define YPAD_ 97
__global__ __launch_bounds__(256) void k_ytail(const float* __restrict__ y2,
                                               const float2* __restrict__ part,
                                               const float* __restrict__ g,
                                               const float* __restrict__ bb,
                                               const unsigned int* __restrict__ P2,
                                               const unsigned short* __restrict__ wbp,
                                               const float* __restrict__ out_b,
                                               float* __restrict__ out) {
    __shared__ float scs[BC_], shs[BC_];
    __shared__ float cfs[BC_][32];
    __shared__ unsigned int sYh[32 * YPAD_];
    __shared__ unsigned int sYl[32 * YPAD_];

    int bid = blockIdx.x;
    int n = bid >> 7, px0 = (bid & 127) << 5;
    int t = threadIdx.x;

    int px = t & 31, cg = t >> 5;
    unsigned int u[4][9];
    {
        const unsigned int* Pb = P2 + (((size_t)n * P2CH_) << 12) + px0 + px;
        #pragma unroll
        for (int cc = 0; cc < 4; cc++) {
            int c = cg * 4 + cc;
            #pragma unroll
            for (int tp = 0; tp < 9; tp++)
                u[cc][tp] = Pb[(size_t)(tp * 32 + c) << 12];
        }
    }

    if (t < BC_) {
        float s = 0.f, s2 = 0.f;
        #pragma unroll
        for (int j = 0; j < 8; j++) { float2 p = part[t * 8 + j]; s += p.x; s2 += p.y; }
        float mu = s / (float)NHW_, var = s2 / (float)NHW_ - mu * mu;
        float sc = g[t] * rsqrtf(var + 1e-5f);
        scs[t] = sc; shs[t] = bb[t] - mu * sc;
    }
    __syncthreads();

    for (int i = t; i < BC_ * 32; i += 256) {
        int ch = i >> 5, pxx = i & 31;
        float v = y2[(((size_t)n * BC_ + ch) << 12) + px0 + pxx];
        cfs[ch][pxx] = tanhf(v * scs[ch] + shs[ch]);
    }
    __syncthreads();

    // phase 2: pack over cc-pairs -> v_pk_fma_f32
    {
        f32x2 pv2[2][TB_];   // j: (c pair 2j, 2j+1)
        #pragma unroll
        for (int j = 0; j < 2; j++)
            #pragma unroll
            for (int tp = 0; tp < 9; tp++) {
                pv2[j][2 * tp].x     = __uint_as_float(u[2 * j][tp] << 16);
                pv2[j][2 * tp].y     = __uint_as_float(u[2 * j + 1][tp] << 16);
                pv2[j][2 * tp + 1].x = __uint_as_float(u[2 * j][tp] & 0xffff0000u);
                pv2[j][2 * tp + 1].y = __uint_as_float(u[2 * j + 1][tp] & 0xffff0000u);
            }
        f32x2 ym2[2][NB_];
        #pragma unroll
        for (int j = 0; j < 2; j++)
            #pragma unroll
            for (int m = 0; m < NB_; m++) ym2[j][m] = (f32x2){0.f, 0.f};
        #pragma unroll
        for (int m = 0; m < NB_; m++)
            #pragma unroll
            for (int tt = 0; tt < TB_; tt++) {
                float cfv = cfs[m * TB_ + tt][px];
                f32x2 c2 = (f32x2){cfv, cfv};
                ym2[0][m] += c2 * pv2[0][tt];
                ym2[1][m] += c2 * pv2[1][tt];
            }
        #pragma unroll
        for (int j = 0; j < 2; j++) {
            #pragma unroll
            for (int half = 0; half < 2; half++) {
                int c = cg * 4 + 2 * j + half;
                #pragma unroll
                for (int jj = 0; jj < 3; jj++) {
                    float y0 = half ? ym2[j][2 * jj].y     : ym2[j][2 * jj].x;
                    float y1v = half ? ym2[j][2 * jj + 1].y : ym2[j][2 * jj + 1].x;
                    unsigned short h0 = f2bf(y0);
                    unsigned short h1 = f2bf(y1v);
                    unsigned short l0 = f2bf(y0 - bf2f(h0));
                    unsigned short l1 = f2bf(y1v - bf2f(h1));
                    sYh[px * YPAD_ + c * 3 + jj] = (unsigned int)h0 | ((unsigned int)h1 << 16);
                    sYl[px * YPAD_ + c * 3 + jj] = (unsigned int)l0 | ((unsigned int)l1 << 16);
                }
            }
        }
    }
    __syncthreads();

    int lane = t & 63, wv = t >> 6;
    int q = lane >> 4, n15 = lane & 15;
    f32x4 acc[2];
    acc[0] = (f32x4){0.f, 0.f, 0.f, 0.f};
    acc[1] = (f32x4){0.f, 0.f, 0.f, 0.f};
    #pragma unroll
    for (int ks = 0; ks < 6; ks++) {
        short8 ah = *(const short8*)(wbp + (wv * 16 + n15) * DDIM_ + ks * 32 + q * 8);
        short8 al = *(const short8*)(wbp + OUT_ * DDIM_ + (wv * 16 + n15) * DDIM_ + ks * 32 + q * 8);
        #pragma unroll
        for (int nt = 0; nt < 2; nt++) {
            short8 bh = frag4(sYh + (nt * 16 + n15) * YPAD_ + ks * 16 + q * 4);
            short8 bl = frag4(sYl + (nt * 16 + n15) * YPAD_ + ks * 16 + q * 4);
            acc[nt] = __builtin_amdgcn_mfma_f32_16x16x32_bf16(ah, bh, acc[nt], 0, 0, 0);
            acc[nt] = __builtin_amdgcn_mfma_f32_16x16x32_bf16(ah, bl, acc[nt], 0, 0, 0);
            acc[nt] = __builtin_amdgcn_mfma_f32_16x16x32_bf16(al, bh, acc[nt], 0, 0, 0);
        }
    }
    #pragma unroll
    for (int nt = 0; nt < 2; nt++)
        #pragma unroll
        for (int reg = 0; reg < 4; reg++) {
            int o = wv * 16 + q * 4 + reg;
            out[(((size_t)n * OUT_ + o) << 12) + px0 + nt * 16 + n15] = acc[nt][reg] + out_b[o];
        }
}

extern "C" void kernel_launch(void* const* d_in, const int* in_sizes, int n_in,
                              void* d_out, int out_size, void* d_ws, size_t ws_size,
                              hipStream_t stream) {
    const float* x       = (const float*)d_in[0];
    const float* conv1_w = (const float*)d_in[1];
    const float* conv1_b = (const float*)d_in[2];
    const float* bn1_g   = (const float*)d_in[3];
    const float* bn1_b   = (const float*)d_in[4];
    const float* conv2_w = (const float*)d_in[5];
    const float* conv2_b = (const float*)d_in[6];
    const float* bn2_g   = (const float*)d_in[7];
    const float* bn2_b   = (const float*)d_in[8];
    const float* bases   = (const float*)d_in[9];
    const float* out_w   = (const float*)d_in[10];
    const float* out_b   = (const float*)d_in[11];
    float* out = (float*)d_out;

    float* y1  = (float*)d_ws;                       // 2,097,152 f32
    float* y2  = y1 + (size_t)N_ * INTER_ * HW_;     // 3,538,944 f32
    unsigned int* P2 = (unsigned int*)(y2 + (size_t)N_ * BC_ * HW_); // 9,437,184 dw
    unsigned short* xb  = (unsigned short*)(P2 + (size_t)N_ * P2CH_ * HW_); // 1,048,576
    unsigned short* y1b = xb + (size_t)NHW_ * C_;    // 2,097,152
    unsigned short* wb1 = y1b + (size_t)NHW_ * INTER_; // 18,432
    unsigned short* wb2 = wb1 + 9 * 64 * 32;         // 73,728
    unsigned short* wbp = wb2 + 9 * 128 * 64;        // 24,576 (hi + lo)
    float2* part1 = (float2*)(wbp + 2 * OUT_ * DDIM_); // 64*8
    float2* part2 = part1 + INTER_ * 8;              // 108*8

    k_front<<<1944, 256, 0, stream>>>(x, bases, conv1_w, conv2_w, out_w,
                                      xb, wb1, wb2, wbp, P2);

    k_conv3<C_, 64, 1, 64, 1><<<N_ * 64, 256, 0, stream>>>(
        xb, wb1, conv1_b, y1, INTER_);
    k_bnpart<<<INTER_ * 8, 256, 0, stream>>>(y1, part1, INTER_);
    k_bntr<<<512, 256, 0, stream>>>(y1, part1, bn1_g, bn1_b, y1b);

    k_conv3<INTER_, 16, 2, 128, 7><<<N_ * 32 * 7, 256, 0, stream>>>(
        y1b, wb2, conv2_b, y2, BC_);
    k_bnpart<<<BC_ * 8, 256, 0, stream>>>(y2, part2, BC_);

    k_ytail<<<1024, 256, 0, stream>>>(y2, (const float2*)part2, bn2_g, bn2_b,
                                      P2, wbp, out_b, out);
}